// Round 11
// baseline (103.855 us; speedup 1.0000x reference)
//
#include <hip/hip_runtime.h>
#include <hip/hip_bf16.h>
#include <cstdint>

#define GLOBAL_AS __attribute__((address_space(1)))
#define LDS_AS    __attribute__((address_space(3)))

typedef float f4v  __attribute__((ext_vector_type(4)));
typedef unsigned short u8s __attribute__((ext_vector_type(8)));

#define NEGV (-1e7f)

__device__ __forceinline__ void gload_lds16(const void* g, void* l) {
  __builtin_amdgcn_global_load_lds((const GLOBAL_AS uint32_t*)g,
                                   (LDS_AS uint32_t*)l, 16, 0, 0);
}

__device__ __forceinline__ unsigned char f2fp8(float x) {
  return (unsigned char)(__builtin_amdgcn_cvt_pk_fp8_f32(x, x, 0, false) & 0xff);
}

// ------- combined: bert f32 -> fp8 (x16 scale)  +  W1 transpose -> fp8 (x128 scale) -------
__global__ __launch_bounds__(256) void cvt_all(const float* __restrict__ bert,
                                               unsigned char* __restrict__ afp8,
                                               const float* __restrict__ w1,
                                               unsigned char* __restrict__ w1t) {
  __shared__ float tile[32][33];
  if (blockIdx.x < 2048) {
    const int n8 = 16384 * 1024 / 8;
    int i = blockIdx.x * 256 + threadIdx.x;
    for (; i < n8; i += 2048 * 256) {
      float4 a = ((const float4*)bert)[2 * i + 0];
      float4 b = ((const float4*)bert)[2 * i + 1];
      int lo = __builtin_amdgcn_cvt_pk_fp8_f32(a.x * 16.f, a.y * 16.f, 0, false);
      lo     = __builtin_amdgcn_cvt_pk_fp8_f32(a.z * 16.f, a.w * 16.f, lo, true);
      int hi = __builtin_amdgcn_cvt_pk_fp8_f32(b.x * 16.f, b.y * 16.f, 0, false);
      hi     = __builtin_amdgcn_cvt_pk_fp8_f32(b.z * 16.f, b.w * 16.f, hi, true);
      ((int2*)afp8)[i] = make_int2(lo, hi);
    }
  } else {
    int bb = blockIdx.x - 2048;
    int bx = bb & 31;
    int by = bb >> 5;
    int tx = threadIdx.x & 31;
    int ty = threadIdx.x >> 5;
#pragma unroll
    for (int j = 0; j < 4; ++j) {
      int kk = ty + j * 8;
      tile[kk][tx] = w1[(size_t)(by * 32 + kk) * 1024 + bx * 32 + tx];
    }
    __syncthreads();
#pragma unroll
    for (int j = 0; j < 4; ++j) {
      int nn = ty + j * 8;
      w1t[(size_t)(bx * 32 + nn) * 1024 + by * 32 + tx] = f2fp8(tile[tx][nn] * 128.f);
    }
  }
}

// =========== V0 (control, REAL output): R10 fp8 256^2 8-phase, unchanged ===========
__global__ __launch_bounds__(512, 2) void gemm_v0(
    const unsigned char* __restrict__ Afp8,
    const unsigned char* __restrict__ Bfp8,
    const float* __restrict__ b1,
    const float* __restrict__ W2,
    float* __restrict__ partials)             // [4][16384][3]
{
  __shared__ __align__(16) char lds[147456];

  int bid = blockIdx.x;
  int wid = (bid & 7) * 32 + (bid >> 3);
  int mt = wid >> 2;
  int nt = wid & 3;

  int tid  = threadIdx.x;
  int lane = tid & 63;
  int wv   = tid >> 6;
  int wr   = wv >> 2;
  int wc   = wv & 3;

  int laneq = lane & 15;
  int klo8  = (lane >> 4) * 8;
  int sw    = (laneq & 7) << 4;

  const size_t arow0 = (size_t)mt * 256;
  const size_t brow0 = (size_t)nt * 256;

  int scol = ((lane & 7) * 16) ^ ((lane >> 3) << 4);
  const unsigned char* gA = Afp8 + (arow0 + (lane >> 3)) * 1024 + scol
                                 + (size_t)wv * 16 * 1024;
  const unsigned char* gB = Bfp8 + (brow0 + (lane >> 3)) * 1024 + scol
                                 + (size_t)wv * 16 * 1024;

  f4v acc[8][4];
#pragma unroll
  for (int m = 0; m < 8; ++m)
#pragma unroll
    for (int n = 0; n < 4; ++n)
      acc[m][n] = f4v{0.f, 0.f, 0.f, 0.f};

  long a_frag[4][4];
  long b_frag[2][2][4];

  auto STAGE = [&](int ts, int isB, int rh) {
    int ok  = ts < 8;
    int tcl = ok ? ts : 7;
    const unsigned char* g = (isB ? gB : gA) + (size_t)rh * 128 * 1024 + tcl * 128;
    int dst = ok ? (((tcl & 1) << 16) | (isB << 15) | (rh << 14) | (wv << 11))
                 : (131072 + (wv << 11));
    gload_lds16(g,            lds + dst);
    gload_lds16(g + 8 * 1024, lds + dst + 1024);
  };

  auto READ_A = [&](int buf, int mq) {
    const char* p = lds + (buf << 16) + (wr << 14) + mq * 8192 + laneq * 128;
#pragma unroll
    for (int m = 0; m < 4; ++m)
#pragma unroll
      for (int kh = 0; kh < 4; ++kh)
        a_frag[m][kh] = *(const long*)(p + m * 2048 + ((kh * 32 + klo8) ^ sw));
  };
  auto READ_B = [&](int buf, int np) {
    const char* p = lds + (buf << 16) + 32768 + ((wc >> 1) << 14)
                        + ((wc & 1) * 64 + laneq) * 128 + np * 4096;
#pragma unroll
    for (int n2 = 0; n2 < 2; ++n2)
#pragma unroll
      for (int kh = 0; kh < 4; ++kh)
        b_frag[np][n2][kh] = *(const long*)(p + n2 * 2048 + ((kh * 32 + klo8) ^ sw));
  };
  auto MFMA_Q = [&](int mq, int np) {
    __builtin_amdgcn_s_setprio(1);
#pragma unroll
    for (int m = 0; m < 4; ++m)
#pragma unroll
      for (int n2 = 0; n2 < 2; ++n2)
#pragma unroll
        for (int kh = 0; kh < 4; ++kh)
          acc[mq*4+m][np*2+n2] = __builtin_amdgcn_mfma_f32_16x16x32_fp8_fp8(
              a_frag[m][kh], b_frag[np][n2][kh], acc[mq*4+m][np*2+n2], 0, 0, 0);
    __builtin_amdgcn_s_setprio(0);
  };

#define BAR  __builtin_amdgcn_s_barrier()
#define SB0  __builtin_amdgcn_sched_barrier(0)
#define VM4  asm volatile("s_waitcnt vmcnt(4)" ::: "memory")

  STAGE(0,1,0); STAGE(0,0,0); STAGE(0,0,1); STAGE(0,1,1);
  STAGE(1,1,0); STAGE(1,0,0);
  VM4; BAR; SB0;

  for (int i = 0; i < 4; ++i) {
    int T = 2 * i;
    READ_A(0,0); READ_B(0,0); STAGE(T+1,0,1);
    BAR; SB0; MFMA_Q(0,0); BAR;
    READ_B(0,1);             STAGE(T+1,1,1);
    BAR; SB0; MFMA_Q(0,1); BAR;
    READ_A(0,1);             STAGE(T+2,1,0);
    BAR; SB0; MFMA_Q(1,1); BAR;
                             STAGE(T+2,0,0);
    VM4;
    BAR; SB0; MFMA_Q(1,0); BAR;
    READ_A(1,0); READ_B(1,0); STAGE(T+2,0,1);
    BAR; SB0; MFMA_Q(0,0); BAR;
    READ_B(1,1);             STAGE(T+2,1,1);
    BAR; SB0; MFMA_Q(0,1); BAR;
    READ_A(1,1);             STAGE(T+3,1,0);
    BAR; SB0; MFMA_Q(1,1); BAR;
                             STAGE(T+3,0,0);
    VM4;
    BAR; SB0; MFMA_Q(1,0); BAR;
  }

#undef BAR
#undef SB0
#undef VM4

  const float DS = 1.0f / 2048.0f;
  float b1v[4];
  float w2v[4][3];
#pragma unroll
  for (int n = 0; n < 4; ++n) {
    int gc = nt * 256 + wc * 64 + n * 16 + laneq;
    b1v[n] = b1[gc];
    w2v[n][0] = W2[gc * 3 + 0];
    w2v[n][1] = W2[gc * 3 + 1];
    w2v[n][2] = W2[gc * 3 + 2];
  }

  float* red = (float*)lds;
#pragma unroll
  for (int m = 0; m < 8; ++m) {
#pragma unroll
    for (int q = 0; q < 4; ++q) {
      float p0 = 0.f, p1 = 0.f, p2 = 0.f;
#pragma unroll
      for (int n = 0; n < 4; ++n) {
        float h = acc[m][n][q] * DS + b1v[n];
        h = fmaxf(h, 0.f);
        p0 += h * w2v[n][0];
        p1 += h * w2v[n][1];
        p2 += h * w2v[n][2];
      }
#pragma unroll
      for (int s = 1; s < 16; s <<= 1) {
        p0 += __shfl_xor(p0, s, 64);
        p1 += __shfl_xor(p1, s, 64);
        p2 += __shfl_xor(p2, s, 64);
      }
      if ((lane & 15) == 0) {
        int row = wr * 128 + m * 16 + (lane >> 4) * 4 + q;
        red[(wc * 256 + row) * 3 + 0] = p0;
        red[(wc * 256 + row) * 3 + 1] = p1;
        red[(wc * 256 + row) * 3 + 2] = p2;
      }
    }
  }
  __syncthreads();
  if (tid < 256) {
    float s0 = 0.f, s1 = 0.f, s2 = 0.f;
#pragma unroll
    for (int w = 0; w < 4; ++w) {
      s0 += red[(w * 256 + tid) * 3 + 0];
      s1 += red[(w * 256 + tid) * 3 + 1];
      s2 += red[(w * 256 + tid) * 3 + 2];
    }
    size_t o = ((size_t)nt * 16384 + (size_t)mt * 256 + tid) * 3;
    partials[o + 0] = s0;
    partials[o + 1] = s1;
    partials[o + 2] = s2;
  }
}

// =========== V1 (A/B probe, dummy output): fp8 128^2, BK=128, 4 waves, 2 blocks/CU ===========
// LDS 64 KB (2 bufs x (16K A + 16K B)), no dummy slot (stages guarded t<7).
// Counted vmcnt(8): tile t+1's 8 loads stay in flight across tile t's compute.
// Tests the convoy/occupancy theory: co-resident block hides barrier/latency slop.
__global__ __launch_bounds__(256, 2) void gemm_v1(
    const unsigned char* __restrict__ Afp8,
    const unsigned char* __restrict__ Bfp8,
    const float* __restrict__ b1,
    const float* __restrict__ W2,
    float* __restrict__ partials)             // [8][16384][3] (dummy)
{
  __shared__ __align__(16) char lds[65536];

  // bijective XCD swizzle: 1024 wgs, 8 XCDs, 128 per XCD
  int bid = blockIdx.x;
  int wid = (bid & 7) * 128 + (bid >> 3);
  int mt = wid >> 3;   // 0..127
  int nt = wid & 7;    // 0..7

  int tid  = threadIdx.x;
  int lane = tid & 63;
  int wv   = tid >> 6;  // 0..3
  int wr   = wv >> 1;   // 0..1: rows wr*64..+63
  int wc   = wv & 1;    // 0..1: cols wc*64..+63

  int laneq = lane & 15;
  int klo8  = (lane >> 4) * 8;
  int sw    = (laneq & 7) << 4;

  const size_t arow0 = (size_t)mt * 128;
  const size_t brow0 = (size_t)nt * 128;

  int scol = ((lane & 7) * 16) ^ ((lane >> 3) << 4);
  const unsigned char* gA = Afp8 + (arow0 + wv * 32 + (lane >> 3)) * 1024 + scol;
  const unsigned char* gB = Bfp8 + (brow0 + wv * 32 + (lane >> 3)) * 1024 + scol;

  f4v acc[4][4];
#pragma unroll
  for (int m = 0; m < 4; ++m)
#pragma unroll
    for (int n = 0; n < 4; ++n)
      acc[m][n] = f4v{0.f, 0.f, 0.f, 0.f};

  // stage tile t: per wave rows wv*32..+31 of A and B (4 gload each)
  auto STAGE = [&](int t) {
    char* base = lds + ((t & 1) << 15);
#pragma unroll
    for (int c = 0; c < 4; ++c) {
      gload_lds16(gA + (size_t)(c * 8) * 1024 + t * 128, base + (wv * 4 + c) * 1024);
      gload_lds16(gB + (size_t)(c * 8) * 1024 + t * 128, base + 16384 + (wv * 4 + c) * 1024);
    }
  };

  auto COMPUTE = [&](int buf) {
    const char* As = lds + (buf << 15);
    const char* Bs = As + 16384;
    long av[4][4], bv[4][4];
#pragma unroll
    for (int m = 0; m < 4; ++m) {
      int ra = wr * 64 + m * 16 + laneq;
      const char* p = As + ra * 128;
#pragma unroll
      for (int kh = 0; kh < 4; ++kh)
        av[m][kh] = *(const long*)(p + ((kh * 32 + klo8) ^ sw));
    }
#pragma unroll
    for (int n = 0; n < 4; ++n) {
      int rb = wc * 64 + n * 16 + laneq;
      const char* p = Bs + rb * 128;
#pragma unroll
      for (int kh = 0; kh < 4; ++kh)
        bv[n][kh] = *(const long*)(p + ((kh * 32 + klo8) ^ sw));
    }
    __builtin_amdgcn_s_setprio(1);
#pragma unroll
    for (int m = 0; m < 4; ++m)
#pragma unroll
      for (int n = 0; n < 4; ++n)
#pragma unroll
        for (int kh = 0; kh < 4; ++kh)
          acc[m][n] = __builtin_amdgcn_mfma_f32_16x16x32_fp8_fp8(
              av[m][kh], bv[n][kh], acc[m][n], 0, 0, 0);
    __builtin_amdgcn_s_setprio(0);
  };

  STAGE(0);
  asm volatile("s_waitcnt vmcnt(0)" ::: "memory");
  __builtin_amdgcn_s_barrier();

  for (int t = 0; t < 8; ++t) {
    if (t < 7) {
      STAGE(t + 1);
      asm volatile("s_waitcnt vmcnt(8)" ::: "memory");  // tile t drained; t+1 in flight
    } else {
      asm volatile("s_waitcnt vmcnt(0)" ::: "memory");
    }
    __builtin_amdgcn_s_barrier();
    __builtin_amdgcn_sched_barrier(0);
    COMPUTE(t & 1);
    __builtin_amdgcn_s_barrier();
  }

  // epilogue (R8-verified 4-wave form), descale
  const float DS = 1.0f / 2048.0f;
  float b1v[4];
  float w2v[4][3];
#pragma unroll
  for (int n = 0; n < 4; ++n) {
    int gc = nt * 128 + wc * 64 + n * 16 + laneq;
    b1v[n] = b1[gc];
    w2v[n][0] = W2[gc * 3 + 0];
    w2v[n][1] = W2[gc * 3 + 1];
    w2v[n][2] = W2[gc * 3 + 2];
  }
  float* red = (float*)lds;
#pragma unroll
  for (int m = 0; m < 4; ++m) {
#pragma unroll
    for (int q = 0; q < 4; ++q) {
      float p0 = 0.f, p1 = 0.f, p2 = 0.f;
#pragma unroll
      for (int n = 0; n < 4; ++n) {
        float h = acc[m][n][q] * DS + b1v[n];
        h = fmaxf(h, 0.f);
        p0 += h * w2v[n][0];
        p1 += h * w2v[n][1];
        p2 += h * w2v[n][2];
      }
#pragma unroll
      for (int s = 1; s < 16; s <<= 1) {
        p0 += __shfl_xor(p0, s, 64);
        p1 += __shfl_xor(p1, s, 64);
        p2 += __shfl_xor(p2, s, 64);
      }
      if ((lane & 15) == 0) {
        int row = wr * 64 + m * 16 + (lane >> 4) * 4 + q;
        red[(wc * 128 + row) * 3 + 0] = p0;
        red[(wc * 128 + row) * 3 + 1] = p1;
        red[(wc * 128 + row) * 3 + 2] = p2;
      }
    }
  }
  __syncthreads();
  if (tid < 128) {
    float s0 = 0.f, s1 = 0.f, s2 = 0.f;
#pragma unroll
    for (int w = 0; w < 2; ++w) {
      s0 += red[(w * 128 + tid) * 3 + 0];
      s1 += red[(w * 128 + tid) * 3 + 1];
      s2 += red[(w * 128 + tid) * 3 + 2];
    }
    size_t o = ((size_t)nt * 16384 + (size_t)mt * 128 + tid) * 3;
    partials[o + 0] = s0;
    partials[o + 1] = s1;
    partials[o + 2] = s2;
  }
}

// ---------------- finalize: sum partials, log-softmax, gather, logsumexp ----------------
__device__ __forceinline__ float blockReduceSum(float v, float* red, int t) {
#pragma unroll
  for (int s = 32; s >= 1; s >>= 1) v += __shfl_xor(v, s, 64);
  __syncthreads();
  if ((t & 63) == 0) red[t >> 6] = v;
  __syncthreads();
  return red[0] + red[1] + red[2] + red[3];
}

__global__ __launch_bounds__(256) void finalize(
    const float* __restrict__ partials, // [4][16384][3]
    const float* __restrict__ b2,
    const int* __restrict__ seq_mask,
    const int* __restrict__ ans,
    const int* __restrict__ span,
    const int* __restrict__ isbio,
    float* __restrict__ out)
{
  int b = blockIdx.x;
  int t = threadIdx.x;
  __shared__ float lp[512][3];
  __shared__ float red[4];
  __shared__ float seq_ll[9];
  __shared__ int preg;

  float b20 = b2[0], b21 = b2[1], b22 = b2[2];
  const int NP = 16384 * 3;

  for (int l = t; l < 512; l += 256) {
    int gi = b * 512 + l;
    float x0 = b20, x1 = b21, x2 = b22;
#pragma unroll
    for (int w = 0; w < 4; ++w) {
      x0 += partials[w * NP + gi * 3 + 0];
      x1 += partials[w * NP + gi * 3 + 1];
      x2 += partials[w * NP + gi * 3 + 2];
    }
    float mx = fmaxf(x0, fmaxf(x1, x2));
    float lse = mx + logf(expf(x0 - mx) + expf(x1 - mx) + expf(x2 - mx));
    float msk = (float)seq_mask[gi];
    lp[l][0] = (x0 - lse) * msk;
    lp[l][1] = (x1 - lse) * msk;
    lp[l][2] = (x2 - lse) * msk;
  }
  __syncthreads();

  float s = 0.f;
  for (int i = t; i < 8 * 512; i += 256) {
    int m = i >> 9, l = i & 511;
    s += (float)(ans[(b * 8 + m) * 512 + l] * seq_mask[b * 512 + l]);
  }
  s = blockReduceSum(s, red, t);
  if (t == 0) preg = (s > 0.f) ? 1 : 0;
  __syncthreads();
  int ip = preg;

  for (int m = 0; m < 9; ++m) {
    float sll = 0.f, sidx = 0.f;
    for (int l = t; l < 512; l += 256) {
      int idx;
      if (m < 8) idx = ans[(b * 8 + m) * 512 + l] * seq_mask[b * 512 + l];
      else       idx = span[b * 512 + l] * (1 - ip);
      sll  += lp[l][idx];
      sidx += (float)idx;
    }
    sll  = blockReduceSum(sll, red, t);
    sidx = blockReduceSum(sidx, red, t);
    if (t == 0) seq_ll[m] = (sidx > 0.f) ? sll : NEGV;
  }

  if (t == 0) {
    float mx = seq_ll[0];
#pragma unroll
    for (int m = 1; m < 9; ++m) mx = fmaxf(mx, seq_ll[m]);
    float sum = 0.f;
#pragma unroll
    for (int m = 0; m < 9; ++m) sum += expf(seq_ll[m] - mx);
    float lml = mx + logf(sum);
    out[b] = isbio[b] ? lml : NEGV;
  }
}

extern "C" void kernel_launch(void* const* d_in, const int* in_sizes, int n_in,
                              void* d_out, int out_size, void* d_ws, size_t ws_size,
                              hipStream_t stream) {
  const float* bert     = (const float*)d_in[0];
  const int*   seq_mask = (const int*)d_in[1];
  const int*   ans      = (const int*)d_in[4];
  const int*   span     = (const int*)d_in[5];
  const int*   isbio    = (const int*)d_in[6];
  const float* W1       = (const float*)d_in[7];
  const float* b1       = (const float*)d_in[8];
  const float* W2       = (const float*)d_in[9];
  const float* b2       = (const float*)d_in[10];
  float* out = (float*)d_out;

  char* ws = (char*)d_ws;
  float* partials      = (float*)ws;                                      // 768 KB (V0, real)
  unsigned char* Afp8  = (unsigned char*)(ws + (1 << 20));                // 16 MB
  unsigned char* W1T8  = (unsigned char*)(ws + (1 << 20) + (size_t)16384 * 1024); // 1 MB
  float* partials_v1   = (float*)(ws + (20u << 20));                      // 1.5 MB (V1, dummy)

  cvt_all<<<3072, 256, 0, stream>>>(bert, Afp8, W1, W1T8);
  gemm_v0<<<256, 512, 0, stream>>>(Afp8, W1T8, b1, W2, partials);
  finalize<<<32, 256, 0, stream>>>(partials, b2, seq_mask, ans, span, isbio, out);
  gemm_v1<<<1024, 256, 0, stream>>>(Afp8, W1T8, b1, W2, partials_v1);   // A/B probe
}

// Round 12
// 67.970 us; speedup vs baseline: 1.5280x; 1.5280x over previous
//
#include <hip/hip_runtime.h>
#include <hip/hip_bf16.h>
#include <cstdint>

#define GLOBAL_AS __attribute__((address_space(1)))
#define LDS_AS    __attribute__((address_space(3)))

typedef float f4v  __attribute__((ext_vector_type(4)));

#define NEGV (-1e7f)

__device__ __forceinline__ void gload_lds16(const void* g, void* l) {
  __builtin_amdgcn_global_load_lds((const GLOBAL_AS uint32_t*)g,
                                   (LDS_AS uint32_t*)l, 16, 0, 0);
}

__device__ __forceinline__ unsigned char f2fp8(float x) {
  return (unsigned char)(__builtin_amdgcn_cvt_pk_fp8_f32(x, x, 0, false) & 0xff);
}

// ------- combined: bert f32 -> fp8 (x16 scale)  +  W1 transpose -> fp8 (x128 scale) -------
__global__ __launch_bounds__(256) void cvt_all(const float* __restrict__ bert,
                                               unsigned char* __restrict__ afp8,
                                               const float* __restrict__ w1,
                                               unsigned char* __restrict__ w1t) {
  __shared__ float tile[32][33];
  if (blockIdx.x < 2048) {
    const int n8 = 16384 * 1024 / 8;
    int i = blockIdx.x * 256 + threadIdx.x;
    for (; i < n8; i += 2048 * 256) {
      float4 a = ((const float4*)bert)[2 * i + 0];
      float4 b = ((const float4*)bert)[2 * i + 1];
      int lo = __builtin_amdgcn_cvt_pk_fp8_f32(a.x * 16.f, a.y * 16.f, 0, false);
      lo     = __builtin_amdgcn_cvt_pk_fp8_f32(a.z * 16.f, a.w * 16.f, lo, true);
      int hi = __builtin_amdgcn_cvt_pk_fp8_f32(b.x * 16.f, b.y * 16.f, 0, false);
      hi     = __builtin_amdgcn_cvt_pk_fp8_f32(b.z * 16.f, b.w * 16.f, hi, true);
      ((int2*)afp8)[i] = make_int2(lo, hi);
    }
  } else {
    int bb = blockIdx.x - 2048;
    int bx = bb & 31;
    int by = bb >> 5;
    int tx = threadIdx.x & 31;
    int ty = threadIdx.x >> 5;
#pragma unroll
    for (int j = 0; j < 4; ++j) {
      int kk = ty + j * 8;
      tile[kk][tx] = w1[(size_t)(by * 32 + kk) * 1024 + bx * 32 + tx];
    }
    __syncthreads();
#pragma unroll
    for (int j = 0; j < 4; ++j) {
      int nn = ty + j * 8;
      w1t[(size_t)(bx * 32 + nn) * 1024 + by * 32 + tx] = f2fp8(tile[tx][nn] * 128.f);
    }
  }
}

// ---------------- fused GEMM (fp8): h = relu((A16*W128)/2048 + b1); partial logits ----------
// R12 = R11's V1 probe PROMOTED (within-probe A/B: 27us vs V0's 41.5us —
// convoy/occupancy wall confirmed; 2 blocks/CU hides barrier-lockstep slop).
// fp8 e4m3, 128x128 tile, BK=128, 4 waves (2x2 of 64x64), 64 KB LDS
// (2 bufs x (16K A + 16K B)) -> __launch_bounds__(256,2) = 2 blocks/CU.
// Counted vmcnt(8): tile t+1's 8 gload_lds stay in flight across tile t's
// compute; single drain per tile. XOR swizzle both-sides (rule 21), verified
// byte-identical read path to R10 (absmax 4.0). Scales: A x16, W1 x128 ->
// acc/2048 in epilogue. Epilogue: R8-verified atomic-free coalesced store.
__global__ __launch_bounds__(256, 2) void gemm_fused(
    const unsigned char* __restrict__ Afp8,   // [16384][1024] fp8 (bert*16)
    const unsigned char* __restrict__ Bfp8,   // [1024][1024] fp8 (W1^T * 128)
    const float* __restrict__ b1,
    const float* __restrict__ W2,             // [1024][3] f32
    float* __restrict__ partials)             // [8][16384][3] f32
{
  __shared__ __align__(16) char lds[65536];

  // bijective XCD swizzle: 1024 wgs, 8 XCDs, 128 per XCD
  int bid = blockIdx.x;
  int wid = (bid & 7) * 128 + (bid >> 3);
  int mt = wid >> 3;   // 0..127
  int nt = wid & 7;    // 0..7

  int tid  = threadIdx.x;
  int lane = tid & 63;
  int wv   = tid >> 6;  // 0..3
  int wr   = wv >> 1;   // 0..1: rows wr*64..+63
  int wc   = wv & 1;    // 0..1: cols wc*64..+63

  int laneq = lane & 15;
  int klo8  = (lane >> 4) * 8;
  int sw    = (laneq & 7) << 4;

  const size_t arow0 = (size_t)mt * 128;
  const size_t brow0 = (size_t)nt * 128;

  int scol = ((lane & 7) * 16) ^ ((lane >> 3) << 4);   // pre-swizzled source col
  const unsigned char* gA = Afp8 + (arow0 + wv * 32 + (lane >> 3)) * 1024 + scol;
  const unsigned char* gB = Bfp8 + (brow0 + wv * 32 + (lane >> 3)) * 1024 + scol;

  f4v acc[4][4];
#pragma unroll
  for (int m = 0; m < 4; ++m)
#pragma unroll
    for (int n = 0; n < 4; ++n)
      acc[m][n] = f4v{0.f, 0.f, 0.f, 0.f};

  // stage tile t: per wave rows wv*32..+31 of A and B (4 gload each, 8 total)
  auto STAGE = [&](int t) {
    char* base = lds + ((t & 1) << 15);
#pragma unroll
    for (int c = 0; c < 4; ++c) {
      gload_lds16(gA + (size_t)(c * 8) * 1024 + t * 128, base + (wv * 4 + c) * 1024);
      gload_lds16(gB + (size_t)(c * 8) * 1024 + t * 128, base + 16384 + (wv * 4 + c) * 1024);
    }
  };

  auto COMPUTE = [&](int buf) {
    const char* As = lds + (buf << 15);
    const char* Bs = As + 16384;
    long av[4][4], bv[4][4];
#pragma unroll
    for (int m = 0; m < 4; ++m) {
      int ra = wr * 64 + m * 16 + laneq;
      const char* p = As + ra * 128;
#pragma unroll
      for (int kh = 0; kh < 4; ++kh)
        av[m][kh] = *(const long*)(p + ((kh * 32 + klo8) ^ sw));
    }
#pragma unroll
    for (int n = 0; n < 4; ++n) {
      int rb = wc * 64 + n * 16 + laneq;
      const char* p = Bs + rb * 128;
#pragma unroll
      for (int kh = 0; kh < 4; ++kh)
        bv[n][kh] = *(const long*)(p + ((kh * 32 + klo8) ^ sw));
    }
    __builtin_amdgcn_s_setprio(1);
#pragma unroll
    for (int m = 0; m < 4; ++m)
#pragma unroll
      for (int n = 0; n < 4; ++n)
#pragma unroll
        for (int kh = 0; kh < 4; ++kh)
          acc[m][n] = __builtin_amdgcn_mfma_f32_16x16x32_fp8_fp8(
              av[m][kh], bv[n][kh], acc[m][n], 0, 0, 0);
    __builtin_amdgcn_s_setprio(0);
  };

  STAGE(0);
  asm volatile("s_waitcnt vmcnt(0)" ::: "memory");
  __builtin_amdgcn_s_barrier();

  for (int t = 0; t < 8; ++t) {
    if (t < 7) {
      STAGE(t + 1);
      asm volatile("s_waitcnt vmcnt(8)" ::: "memory");  // tile t drained; t+1 in flight
    } else {
      asm volatile("s_waitcnt vmcnt(0)" ::: "memory");
    }
    __builtin_amdgcn_s_barrier();
    __builtin_amdgcn_sched_barrier(0);
    COMPUTE(t & 1);
    __builtin_amdgcn_s_barrier();
  }

  // ---- epilogue: h = relu(acc/2048 + b1); p = h*W2; shfl-reduce; LDS-reduce; store ----
  const float DS = 1.0f / 2048.0f;   // undo A x16, W1 x128
  float b1v[4];
  float w2v[4][3];
#pragma unroll
  for (int n = 0; n < 4; ++n) {
    int gc = nt * 128 + wc * 64 + n * 16 + laneq;
    b1v[n] = b1[gc];
    w2v[n][0] = W2[gc * 3 + 0];
    w2v[n][1] = W2[gc * 3 + 1];
    w2v[n][2] = W2[gc * 3 + 2];
  }
  float* red = (float*)lds;   // [2 wc][128 rows][3] f32 = 3 KB (K-loop LDS dead)
#pragma unroll
  for (int m = 0; m < 4; ++m) {
#pragma unroll
    for (int q = 0; q < 4; ++q) {
      float p0 = 0.f, p1 = 0.f, p2 = 0.f;
#pragma unroll
      for (int n = 0; n < 4; ++n) {
        float h = acc[m][n][q] * DS + b1v[n];
        h = fmaxf(h, 0.f);
        p0 += h * w2v[n][0];
        p1 += h * w2v[n][1];
        p2 += h * w2v[n][2];
      }
#pragma unroll
      for (int s = 1; s < 16; s <<= 1) {
        p0 += __shfl_xor(p0, s, 64);
        p1 += __shfl_xor(p1, s, 64);
        p2 += __shfl_xor(p2, s, 64);
      }
      if ((lane & 15) == 0) {
        int row = wr * 64 + m * 16 + (lane >> 4) * 4 + q;   // 0..127
        red[(wc * 128 + row) * 3 + 0] = p0;
        red[(wc * 128 + row) * 3 + 1] = p1;
        red[(wc * 128 + row) * 3 + 2] = p2;
      }
    }
  }
  __syncthreads();
  if (tid < 128) {
    float s0 = 0.f, s1 = 0.f, s2 = 0.f;
#pragma unroll
    for (int w = 0; w < 2; ++w) {
      s0 += red[(w * 128 + tid) * 3 + 0];
      s1 += red[(w * 128 + tid) * 3 + 1];
      s2 += red[(w * 128 + tid) * 3 + 2];
    }
    size_t o = ((size_t)nt * 16384 + (size_t)mt * 128 + tid) * 3;
    partials[o + 0] = s0;
    partials[o + 1] = s1;
    partials[o + 2] = s2;
  }
}

// ---------------- finalize: sum 8 partials, log-softmax, gather, logsumexp ----------------
__device__ __forceinline__ float blockReduceSum(float v, float* red, int t) {
#pragma unroll
  for (int s = 32; s >= 1; s >>= 1) v += __shfl_xor(v, s, 64);
  __syncthreads();
  if ((t & 63) == 0) red[t >> 6] = v;
  __syncthreads();
  return red[0] + red[1] + red[2] + red[3];
}

__global__ __launch_bounds__(256) void finalize(
    const float* __restrict__ partials, // [8][16384][3]
    const float* __restrict__ b2,       // [3]
    const int* __restrict__ seq_mask,   // [32][512]
    const int* __restrict__ ans,        // [32][8][512]
    const int* __restrict__ span,       // [32][512]
    const int* __restrict__ isbio,      // [32]
    float* __restrict__ out)            // [32]
{
  int b = blockIdx.x;
  int t = threadIdx.x;
  __shared__ float lp[512][3];
  __shared__ float red[4];
  __shared__ float seq_ll[9];
  __shared__ int preg;

  float b20 = b2[0], b21 = b2[1], b22 = b2[2];
  const int NP = 16384 * 3;

  for (int l = t; l < 512; l += 256) {
    int gi = b * 512 + l;
    float x0 = b20, x1 = b21, x2 = b22;
#pragma unroll
    for (int w = 0; w < 8; ++w) {
      x0 += partials[w * NP + gi * 3 + 0];
      x1 += partials[w * NP + gi * 3 + 1];
      x2 += partials[w * NP + gi * 3 + 2];
    }
    float mx = fmaxf(x0, fmaxf(x1, x2));
    float lse = mx + logf(expf(x0 - mx) + expf(x1 - mx) + expf(x2 - mx));
    float msk = (float)seq_mask[gi];
    lp[l][0] = (x0 - lse) * msk;
    lp[l][1] = (x1 - lse) * msk;
    lp[l][2] = (x2 - lse) * msk;
  }
  __syncthreads();

  // is_pregen = sum(ans * seq_mask) > 0
  float s = 0.f;
  for (int i = t; i < 8 * 512; i += 256) {
    int m = i >> 9, l = i & 511;
    s += (float)(ans[(b * 8 + m) * 512 + l] * seq_mask[b * 512 + l]);
  }
  s = blockReduceSum(s, red, t);
  if (t == 0) preg = (s > 0.f) ? 1 : 0;
  __syncthreads();
  int ip = preg;

  for (int m = 0; m < 9; ++m) {
    float sll = 0.f, sidx = 0.f;
    for (int l = t; l < 512; l += 256) {
      int idx;
      if (m < 8) idx = ans[(b * 8 + m) * 512 + l] * seq_mask[b * 512 + l];
      else       idx = span[b * 512 + l] * (1 - ip);
      sll  += lp[l][idx];
      sidx += (float)idx;
    }
    sll  = blockReduceSum(sll, red, t);
    sidx = blockReduceSum(sidx, red, t);
    if (t == 0) seq_ll[m] = (sidx > 0.f) ? sll : NEGV;
  }

  if (t == 0) {
    float mx = seq_ll[0];
#pragma unroll
    for (int m = 1; m < 9; ++m) mx = fmaxf(mx, seq_ll[m]);
    float sum = 0.f;
#pragma unroll
    for (int m = 0; m < 9; ++m) sum += expf(seq_ll[m] - mx);
    float lml = mx + logf(sum);
    out[b] = isbio[b] ? lml : NEGV;
  }
}

extern "C" void kernel_launch(void* const* d_in, const int* in_sizes, int n_in,
                              void* d_out, int out_size, void* d_ws, size_t ws_size,
                              hipStream_t stream) {
  const float* bert     = (const float*)d_in[0];
  const int*   seq_mask = (const int*)d_in[1];
  // d_in[2] wordpiece_mask: unused
  // d_in[3] answer_as_text_to_disjoint_bios: unused
  const int*   ans      = (const int*)d_in[4];
  const int*   span     = (const int*)d_in[5];
  const int*   isbio    = (const int*)d_in[6];
  const float* W1       = (const float*)d_in[7];
  const float* b1       = (const float*)d_in[8];
  const float* W2       = (const float*)d_in[9];
  const float* b2       = (const float*)d_in[10];
  float* out = (float*)d_out;

  char* ws = (char*)d_ws;
  float* partials      = (float*)ws;                                    // 1.5 MB, fully written
  unsigned char* Afp8  = (unsigned char*)(ws + (2u << 20));             // 16 MB
  unsigned char* W1T8  = (unsigned char*)(ws + (18u << 20));            // 1 MB

  cvt_all<<<3072, 256, 0, stream>>>(bert, Afp8, W1, W1T8);
  gemm_fused<<<1024, 256, 0, stream>>>(Afp8, W1T8, b1, W2, partials);
  finalize<<<32, 256, 0, stream>>>(partials, b2, seq_mask, ans, span, isbio, out);
}